// Round 11
// baseline (197.323 us; speedup 1.0000x reference)
//
#include <hip/hip_runtime.h>
#include <hip/hip_fp16.h>

#define N_Q   16384
#define C_DIM 128
#define S_CAM 6
#define M_VAL 1400   // 28*50
#define D_Z   8
#define HF    28
#define WF    50
#define QPB   8      // queries per block; 32 lanes/query = (cam-half, head, 8ch)

__device__ __forceinline__ bool mask_any(const unsigned char* __restrict__ mask,
                                         int mflag, size_t mbase){
  if(mflag==0){
    int any=0;
    #pragma unroll
    for(int d=0;d<D_Z;d++) any |= mask[mbase+d];
    return any!=0;
  } else if(mflag==1){
    const int* mp = (const int*)mask;  int any=0;
    #pragma unroll
    for(int d=0;d<D_Z;d++) any |= mp[mbase+d];
    return any!=0;
  } else {
    const long long* mp = (const long long*)mask;  long long any=0;
    #pragma unroll
    for(int d=0;d<D_Z;d++) any |= mp[mbase+d];
    return any!=0;
  }
}

// ---------------------------------------------------------------------------
// v = value @ Wv + bv (8400x128 @ 128x128) -> FP16 workspace.
// Block 0 piggybacks the bev_mask upload-format sniff (0=u8,1=i32,2=i64).
// ---------------------------------------------------------------------------
__global__ __launch_bounds__(256)
void value_proj_kernel(const float* __restrict__ value,
                       const float* __restrict__ Wv,
                       const float* __restrict__ bv,
                       unsigned short* __restrict__ vh16,
                       const unsigned char* __restrict__ mask,
                       int* __restrict__ flag){
  __shared__ float tile[8][C_DIM];
  __shared__ int s_cntA, s_cntB;
  const int tid = threadIdx.x;
  const int col = tid & 127;
  const int rh  = tid >> 7;                    // rows rh*4 .. rh*4+3
  const int r0  = blockIdx.x * 8;
  if(blockIdx.x==0 && tid==0){ s_cntA=0; s_cntB=0; }
  {
    const float4* src = (const float4*)(value + (size_t)r0*C_DIM);
    ((float4*)&tile[0][0])[tid] = src[tid];
  }
  __syncthreads();
  float acc[4];
  const float bias = bv[col];
  #pragma unroll
  for(int r=0;r<4;r++) acc[r]=bias;
  for(int k=0;k<C_DIM;k+=4){
    const float w0 = Wv[(k+0)*C_DIM + col];
    const float w1 = Wv[(k+1)*C_DIM + col];
    const float w2 = Wv[(k+2)*C_DIM + col];
    const float w3 = Wv[(k+3)*C_DIM + col];
    #pragma unroll
    for(int r=0;r<4;r++){
      const float4 t = *(const float4*)&tile[rh*4+r][k];
      acc[r] += t.x*w0 + t.y*w1 + t.z*w2 + t.w*w3;
    }
  }
  #pragma unroll
  for(int r=0;r<4;r++)
    vh16[(size_t)(r0+rh*4+r)*C_DIM + col] =
        __half_as_ushort(__float2half_rn(acc[r]));
  if(blockIdx.x==0){
    int a=0, b=0;
    for(int i=tid;i<1024;i+=256){
      const unsigned char v = mask[i];
      if(((i&3)!=0) && v) a=1;
      if(((i&7)==4) && v) b=1;
    }
    if(a) atomicOr(&s_cntA,1);
    if(b) atomicOr(&s_cntB,1);
    __syncthreads();
    if(tid==0) flag[0] = s_cntA ? 0 : (s_cntB ? 1 : 2);
  }
}

// ---------------------------------------------------------------------------
// Fused deformable attention. 32 lanes/query: lane = (cam-half sg, head,
// 8 channels). Camera loop SPLIT across sg -> per-lane gather chain halves
// (24 points), wave count doubles (8 waves/SIMD = 100% occupancy ceiling),
// coordinate math NOT replicated (it's per (s,p,h)). Partial sums merged
// via one LDS RMW. fp16 uint4 corner loads -> v_pk_fma_f16, no unpack.
// __launch_bounds__(256) only: every forced VGPR cap so far spilled.
// ---------------------------------------------------------------------------
__global__ __launch_bounds__(256)
void fused_deform_kernel(const unsigned short* __restrict__ vh16,
                         const float* __restrict__ query,
                         const float* __restrict__ query_pos,
                         const float* __restrict__ Wo, const float* __restrict__ bo,
                         const float* __restrict__ Wa, const float* __restrict__ ba,
                         const float* __restrict__ ref,
                         const unsigned char* __restrict__ mask,
                         const int* __restrict__ flag,
                         const float* __restrict__ Wout,
                         const float* __restrict__ bout,
                         float* __restrict__ out){
  __shared__ float  qs[QPB][C_DIM+4];        // q staging; reused as slot partials
  __shared__ float  offs[QPB][68];           // 68 mod 32 = 4
  __shared__ float  attns[QPB][36];
  __shared__ float  logits[QPB][36];
  __shared__ float2 refs[QPB][S_CAM*D_Z+1];  // 49 f2 rows: 98 mod 32 = 2
  __shared__ int    activ[QPB][S_CAM];
  __shared__ float  cinv[QPB];

  const int tid = threadIdx.x;
  const int n0  = blockIdx.x * QPB;
  const int mflag = flag[0];
  const int qi = tid >> 5;                   // query in block (0..7)
  const int l  = tid & 31;                   // lane within query group

  // ---- 0) ref prefetch (384 float2; <=2/thread) ----
  float2 rpre0, rpre1;
  {
    const int e = tid;                       // e -> q=e/48, s=(e%48)/8, p=e%8
    const int q = e/48, r = e%48;
    rpre0 = ((const float2*)ref)[((size_t)(r>>3)*N_Q + (n0+q))*D_Z + (r&7)];
  }
  if(tid < 128){
    const int e = tid + 256;
    const int q = e/48, r = e%48;
    rpre1 = ((const float2*)ref)[((size_t)(r>>3)*N_Q + (n0+q))*D_Z + (r&7)];
  }

  // ---- 1) q = query + query_pos (1024 floats = 256 float4) ----
  {
    const float4* qa = (const float4*)(query     + (size_t)n0*C_DIM);
    const float4* qb = (const float4*)(query_pos + (size_t)n0*C_DIM);
    const int r = tid >> 5, c4 = tid & 31;
    float4 A = qa[tid], B = qb[tid];
    *(float4*)&qs[r][c4*4] = make_float4(A.x+B.x, A.y+B.y, A.z+B.z, A.w+B.w);
  }
  __syncthreads();

  // ---- 2) projections: lane l -> off cols l*2, l*2+1; logit col l ----
  {
    float ao0 = bo[l*2+0], ao1 = bo[l*2+1];
    float aa0 = ba[l];
    for(int k=0;k<C_DIM;k++){
      const float qv = qs[qi][k];
      const float2 wo = *(const float2*)&Wo[k*64 + l*2];
      ao0 += qv*wo.x; ao1 += qv*wo.y;
      aa0 += qv*Wa[k*32 + l];
    }
    offs[qi][l*2+0] = ao0;  offs[qi][l*2+1] = ao1;
    logits[qi][l]   = aa0;
  }
  refs[tid/48][tid%48] = rpre0;
  if(tid < 128){
    const int e = tid + 256;
    refs[e/48][e%48] = rpre1;
  }
  if(tid < QPB*S_CAM){
    const int q2 = tid / S_CAM, s = tid % S_CAM;
    activ[q2][s] = mask_any(mask, mflag, ((size_t)s*N_Q + (n0+q2))*D_Z) ? 1 : 0;
  }
  __syncthreads();
  if(tid < 32){                              // softmax over P=8: (q2, h)
    const int q2 = tid >> 2, h = tid & 3;
    const float* L = &logits[q2][h*8];
    float mx = L[0];
    #pragma unroll
    for(int p=1;p<8;p++) mx = fmaxf(mx, L[p]);
    float e[8], ssum = 0.f;
    #pragma unroll
    for(int p=0;p<8;p++){ e[p] = __expf(L[p]-mx); ssum += e[p]; }
    const float inv = 1.f/ssum;
    #pragma unroll
    for(int p=0;p<8;p++) attns[q2][h*8+p] = e[p]*inv;
  } else if(tid >= 256-QPB){
    const int q2 = tid - (256-QPB);
    int c = 0;
    #pragma unroll
    for(int s=0;s<S_CAM;s++) c += activ[q2][s];
    cinv[q2] = 1.f / fmaxf((float)c, 1.f);
  }
  __syncthreads();

  // ---- 3) barrier-free gather: lane = (qi, sg, h, 8ch), 3 cams/lane ----
  const int sg  = l >> 4;                    // camera half: cams sg*3 .. sg*3+2
  const int ll  = l & 15;
  const int gh  = ll >> 2;                   // head
  const int gch = gh*32 + (ll&3)*8;          // first of 8 channels
  __half2 acc0 = __float2half2_rn(0.f);
  __half2 acc1 = acc0, acc2 = acc0, acc3 = acc0;

  for(int s=sg*3; s<sg*3+3; s++){
    if(!activ[qi][s]) continue;
    const unsigned short* vb = vh16 + (size_t)s*M_VAL*C_DIM + gch;
    #pragma unroll 2
    for(int p=0;p<8;p++){                    // point p <-> z-anchor d=p (P//D==1)
      const float2 r2 = refs[qi][s*8+p];
      const float ox = offs[qi][gh*16+p*2+0];
      const float oy = offs[qi][gh*16+p*2+1];
      const float x = fmaf(r2.x, (float)WF, ox - 0.5f);
      const float y = fmaf(r2.y, (float)HF, oy - 0.5f);
      const float x0f = floorf(x), y0f = floorf(y);
      const float fx = x - x0f,    fy = y - y0f;
      const int x0 = (int)x0f, y0 = (int)y0f;
      const int x1 = x0+1,     y1 = y0+1;
      const float at = attns[qi][gh*8+p];
      const float wx0 = (x0>=0 && x0<WF) ? (1.f-fx) : 0.f;
      const float wx1 = (x1>=0 && x1<WF) ? fx       : 0.f;
      const float wy0 = ((y0>=0 && y0<HF) ? (1.f-fy) : 0.f) * at;
      const float wy1 = ((y1>=0 && y1<HF) ? fy       : 0.f) * at;
      const int x0c = min(max(x0,0), WF-1), x1c = min(max(x1,0), WF-1);
      const int y0c = min(max(y0,0), HF-1), y1c = min(max(y1,0), HF-1);
      const __half2 W00 = __float2half2_rn(wx0*wy0);
      const __half2 W01 = __float2half2_rn(wx1*wy0);
      const __half2 W10 = __float2half2_rn(wx0*wy1);
      const __half2 W11 = __float2half2_rn(wx1*wy1);
      const uint4 v00 = *(const uint4*)(vb + (y0c*WF+x0c)*C_DIM);
      const uint4 v01 = *(const uint4*)(vb + (y0c*WF+x1c)*C_DIM);
      const uint4 v10 = *(const uint4*)(vb + (y1c*WF+x0c)*C_DIM);
      const uint4 v11 = *(const uint4*)(vb + (y1c*WF+x1c)*C_DIM);
      #define H2(u) (*reinterpret_cast<const __half2*>(&(u)))
      acc0 = __hfma2(H2(v00.x), W00, acc0);  acc0 = __hfma2(H2(v01.x), W01, acc0);
      acc0 = __hfma2(H2(v10.x), W10, acc0);  acc0 = __hfma2(H2(v11.x), W11, acc0);
      acc1 = __hfma2(H2(v00.y), W00, acc1);  acc1 = __hfma2(H2(v01.y), W01, acc1);
      acc1 = __hfma2(H2(v10.y), W10, acc1);  acc1 = __hfma2(H2(v11.y), W11, acc1);
      acc2 = __hfma2(H2(v00.z), W00, acc2);  acc2 = __hfma2(H2(v01.z), W01, acc2);
      acc2 = __hfma2(H2(v10.z), W10, acc2);  acc2 = __hfma2(H2(v11.z), W11, acc2);
      acc3 = __hfma2(H2(v00.w), W00, acc3);  acc3 = __hfma2(H2(v01.w), W01, acc3);
      acc3 = __hfma2(H2(v10.w), W10, acc3);  acc3 = __hfma2(H2(v11.w), W11, acc3);
      #undef H2
    }
  }

  // ---- 4) merge cam-half partials in qs, then out-proj + residual ----
  const float4 partA = make_float4(__low2float(acc0), __high2float(acc0),
                                   __low2float(acc1), __high2float(acc1));
  const float4 partB = make_float4(__low2float(acc2), __high2float(acc2),
                                   __low2float(acc3), __high2float(acc3));
  __syncthreads();                           // all proj reads of qs are long done; re-sync wave fronts
  if(sg==0){
    *(float4*)&qs[qi][gch]   = partA;
    *(float4*)&qs[qi][gch+4] = partB;
  }
  __syncthreads();
  if(sg==1){
    const float inv = cinv[qi];
    float4 pA = *(const float4*)&qs[qi][gch];
    float4 pB = *(const float4*)&qs[qi][gch+4];
    *(float4*)&qs[qi][gch]   = make_float4((pA.x+partA.x)*inv, (pA.y+partA.y)*inv,
                                           (pA.z+partA.z)*inv, (pA.w+partA.w)*inv);
    *(float4*)&qs[qi][gch+4] = make_float4((pB.x+partB.x)*inv, (pB.y+partB.y)*inv,
                                           (pB.z+partB.z)*inv, (pB.w+partB.w)*inv);
  }
  __syncthreads();
  {
    const int c0 = l*4;                      // 4 output cols per lane
    const int n  = n0 + qi;
    const float4 b4 = *(const float4*)&bout[c0];
    const float4 r4 = *(const float4*)&query[(size_t)n*C_DIM + c0];
    float o0=b4.x+r4.x, o1=b4.y+r4.y, o2=b4.z+r4.z, o3=b4.w+r4.w;
    for(int k=0;k<C_DIM;k++){
      const float sv = qs[qi][k];
      const float4 w = *(const float4*)&Wout[(size_t)k*C_DIM + c0];
      o0 += sv*w.x; o1 += sv*w.y; o2 += sv*w.z; o3 += sv*w.w;
    }
    *(float4*)&out[(size_t)n*C_DIM + c0] = make_float4(o0,o1,o2,o3);
  }
}

extern "C" void kernel_launch(void* const* d_in, const int* in_sizes, int n_in,
                              void* d_out, int out_size, void* d_ws, size_t ws_size,
                              hipStream_t stream){
  const float* query     = (const float*)d_in[0];
  const float* query_pos = (const float*)d_in[1];
  const float* value     = (const float*)d_in[2];
  const float* ref       = (const float*)d_in[3];
  const unsigned char* mask = (const unsigned char*)d_in[4];
  const float* Wv   = (const float*)d_in[5];
  const float* bv   = (const float*)d_in[6];
  const float* Wo   = (const float*)d_in[7];
  const float* bo   = (const float*)d_in[8];
  const float* Wa   = (const float*)d_in[9];
  const float* ba   = (const float*)d_in[10];
  const float* Wout = (const float*)d_in[11];
  const float* bout = (const float*)d_in[12];
  float* out = (float*)d_out;

  int* flag = (int*)d_ws;
  unsigned short* vh16 = (unsigned short*)((char*)d_ws + 64);

  value_proj_kernel<<<(S_CAM*M_VAL)/8, 256, 0, stream>>>(value, Wv, bv, vh16, mask, flag);
  fused_deform_kernel<<<N_Q/QPB, 256, 0, stream>>>(vh16, query, query_pos,
                                                   Wo, bo, Wa, ba, ref, mask, flag,
                                                   Wout, bout, out);
}

// Round 13
// 186.082 us; speedup vs baseline: 1.0604x; 1.0604x over previous
//
#include <hip/hip_runtime.h>

#define N_Q   16384
#define C_DIM 128
#define S_CAM 6
#define M_VAL 1400   // 28*50
#define D_Z   8
#define HF    28
#define WF    50
#define QPB   16     // queries per block; 16 lanes/query = (cam-half, 8x16ch)

typedef float f32x2 __attribute__((ext_vector_type(2)));

__device__ __forceinline__ bool mask_any(const unsigned char* __restrict__ mask,
                                         int mflag, size_t mbase){
  if(mflag==0){
    int any=0;
    #pragma unroll
    for(int d=0;d<D_Z;d++) any |= mask[mbase+d];
    return any!=0;
  } else if(mflag==1){
    const int* mp = (const int*)mask;  int any=0;
    #pragma unroll
    for(int d=0;d<D_Z;d++) any |= mp[mbase+d];
    return any!=0;
  } else {
    const long long* mp = (const long long*)mask;  long long any=0;
    #pragma unroll
    for(int d=0;d<D_Z;d++) any |= mp[mbase+d];
    return any!=0;
  }
}

// fp8x16 corner accumulate: 16 channels from one uint4, weight wgt.
__device__ __forceinline__ void corner_acc(const uint4 cv, const float wgt,
                                           float* __restrict__ acc){
  const unsigned dw[4] = {cv.x, cv.y, cv.z, cv.w};
  #pragma unroll
  for(int j=0;j<4;j++){
    const f32x2 lo = __builtin_amdgcn_cvt_pk_f32_fp8(dw[j], false);
    const f32x2 hi = __builtin_amdgcn_cvt_pk_f32_fp8(dw[j], true);
    acc[j*4+0] += wgt*lo[0];  acc[j*4+1] += wgt*lo[1];
    acc[j*4+2] += wgt*hi[0];  acc[j*4+3] += wgt*hi[1];
  }
}

// ---------------------------------------------------------------------------
// v = value @ Wv + bv (8400x128 @ 128x128) -> FP8 e4m3 workspace (HW cvt;
// same HW format encode+decode -> self-consistent roundtrip). Halves gather
// bytes AND lane-requests vs fp16 (R11 showed a saturated per-CU memory pipe:
// occupancy 33%->61% left dur unchanged).
// Block 0 piggybacks the bev_mask upload-format sniff (0=u8,1=i32,2=i64).
// ---------------------------------------------------------------------------
__global__ __launch_bounds__(256)
void value_proj_kernel(const float* __restrict__ value,
                       const float* __restrict__ Wv,
                       const float* __restrict__ bv,
                       unsigned char* __restrict__ v8,
                       const unsigned char* __restrict__ mask,
                       int* __restrict__ flag){
  __shared__ float tile[8][C_DIM];
  __shared__ int s_cntA, s_cntB;
  const int tid = threadIdx.x;
  const int col = tid & 127;
  const int rh  = tid >> 7;                    // rows rh*4 .. rh*4+3
  const int r0  = blockIdx.x * 8;
  if(blockIdx.x==0 && tid==0){ s_cntA=0; s_cntB=0; }
  {
    const float4* src = (const float4*)(value + (size_t)r0*C_DIM);
    ((float4*)&tile[0][0])[tid] = src[tid];
  }
  __syncthreads();
  float acc[4];
  const float bias = bv[col];
  #pragma unroll
  for(int r=0;r<4;r++) acc[r]=bias;
  for(int k=0;k<C_DIM;k+=4){
    const float w0 = Wv[(k+0)*C_DIM + col];
    const float w1 = Wv[(k+1)*C_DIM + col];
    const float w2 = Wv[(k+2)*C_DIM + col];
    const float w3 = Wv[(k+3)*C_DIM + col];
    #pragma unroll
    for(int r=0;r<4;r++){
      const float4 t = *(const float4*)&tile[rh*4+r][k];
      acc[r] += t.x*w0 + t.y*w1 + t.z*w2 + t.w*w3;
    }
  }
  #pragma unroll
  for(int r=0;r<4;r++){
    const int pk = __builtin_amdgcn_cvt_pk_fp8_f32(acc[r], acc[r], 0, false);
    v8[(size_t)(r0+rh*4+r)*C_DIM + col] = (unsigned char)(pk & 0xff);
  }
  if(blockIdx.x==0){
    int a=0, b=0;
    for(int i=tid;i<1024;i+=256){
      const unsigned char v = mask[i];
      if(((i&3)!=0) && v) a=1;
      if(((i&7)==4) && v) b=1;
    }
    if(a) atomicOr(&s_cntA,1);
    if(b) atomicOr(&s_cntB,1);
    __syncthreads();
    if(tid==0) flag[0] = s_cntA ? 0 : (s_cntB ? 1 : 2);
  }
}

// ---------------------------------------------------------------------------
// Fused deformable attention. 16 lanes/query: lane = (cam-half sg, 16-ch
// group). FP8 gather: one 16B load = 16 channels -> per (q,s,p) only 32
// lane-requests / 512B (half of fp16). Decode 2 fp8 -> 2 f32 per
// v_cvt_pk_f32_fp8, f32 accumulate. Barrier-free gather; partials merged
// via LDS RMW. __launch_bounds__(256) only (every forced cap spilled).
// ---------------------------------------------------------------------------
__global__ __launch_bounds__(256)
void fused_deform_kernel(const unsigned char* __restrict__ v8,
                         const float* __restrict__ query,
                         const float* __restrict__ query_pos,
                         const float* __restrict__ Wo, const float* __restrict__ bo,
                         const float* __restrict__ Wa, const float* __restrict__ ba,
                         const float* __restrict__ ref,
                         const unsigned char* __restrict__ mask,
                         const int* __restrict__ flag,
                         const float* __restrict__ Wout,
                         const float* __restrict__ bout,
                         float* __restrict__ out){
  __shared__ float  qs[QPB][C_DIM+4];        // q staging; reused as slot partials
  __shared__ float  offs[QPB][68];           // 68 mod 32 = 4
  __shared__ float  attns[QPB][36];
  __shared__ float  logits[QPB][36];
  __shared__ float2 refs[QPB][S_CAM*D_Z+1];  // 49 f2 rows: 98 mod 32 = 2
  __shared__ int    activ[QPB][S_CAM];
  __shared__ float  cinv[QPB];

  const int tid = threadIdx.x;
  const int n0  = blockIdx.x * QPB;
  const int mflag = flag[0];
  const int qi = tid >> 4;                   // query in block (0..15)
  const int l  = tid & 15;                   // lane within query group

  // ---- 0) ref prefetch (768 float2; 3/thread) ----
  float2 rpre[3];
  #pragma unroll
  for(int j=0;j<3;j++){
    const int e = tid + 256*j;               // e -> q=e/48, s=(e%48)/8, p=e%8
    const int q = e/48, r = e%48;
    rpre[j] = ((const float2*)ref)[((size_t)(r>>3)*N_Q + (n0+q))*D_Z + (r&7)];
  }

  // ---- 1) q = query + query_pos ----
  {
    const float4* qa = (const float4*)(query     + (size_t)n0*C_DIM);
    const float4* qb = (const float4*)(query_pos + (size_t)n0*C_DIM);
    #pragma unroll
    for(int j=0;j<2;j++){
      const int idx = tid + 256*j;
      const int r = idx >> 5, c4 = idx & 31;
      float4 A = qa[idx], B = qb[idx];
      *(float4*)&qs[r][c4*4] = make_float4(A.x+B.x, A.y+B.y, A.z+B.z, A.w+B.w);
    }
  }
  __syncthreads();

  // ---- 2) projections: lane l -> off cols l*4.., logit cols l*2.. ----
  {
    float ao0 = bo[l*4+0], ao1 = bo[l*4+1], ao2 = bo[l*4+2], ao3 = bo[l*4+3];
    float aa0 = ba[l*2+0], aa1 = ba[l*2+1];
    for(int k=0;k<C_DIM;k++){
      const float qv = qs[qi][k];
      const float4 wo = *(const float4*)&Wo[k*64 + l*4];
      const float2 wa = *(const float2*)&Wa[k*32 + l*2];
      ao0 += qv*wo.x; ao1 += qv*wo.y; ao2 += qv*wo.z; ao3 += qv*wo.w;
      aa0 += qv*wa.x; aa1 += qv*wa.y;
    }
    offs[qi][l*4+0] = ao0;  offs[qi][l*4+1] = ao1;
    offs[qi][l*4+2] = ao2;  offs[qi][l*4+3] = ao3;
    logits[qi][l*2+0] = aa0;  logits[qi][l*2+1] = aa1;
  }
  #pragma unroll
  for(int j=0;j<3;j++){
    const int e = tid + 256*j;
    refs[e/48][e%48] = rpre[j];
  }
  if(tid < QPB*S_CAM){
    const int q2 = tid / S_CAM, s = tid % S_CAM;
    activ[q2][s] = mask_any(mask, mflag, ((size_t)s*N_Q + (n0+q2))*D_Z) ? 1 : 0;
  }
  __syncthreads();
  if(tid < 64){                              // softmax over P=8: (q2, h)
    const int q2 = tid >> 2, h = tid & 3;
    const float* L = &logits[q2][h*8];
    float mx = L[0];
    #pragma unroll
    for(int p=1;p<8;p++) mx = fmaxf(mx, L[p]);
    float e[8], ssum = 0.f;
    #pragma unroll
    for(int p=0;p<8;p++){ e[p] = __expf(L[p]-mx); ssum += e[p]; }
    const float inv = 1.f/ssum;
    #pragma unroll
    for(int p=0;p<8;p++) attns[q2][h*8+p] = e[p]*inv;
  } else if(tid >= 256-QPB){
    const int q2 = tid - (256-QPB);
    int c = 0;
    #pragma unroll
    for(int s=0;s<S_CAM;s++) c += activ[q2][s];
    cinv[q2] = 1.f / fmaxf((float)c, 1.f);
  }
  __syncthreads();

  // ---- 3) barrier-free FP8 gather: lane = (sg cam-half, 16ch), 3 cams ----
  const int sg  = l >> 3;                    // cams sg*3 .. sg*3+2
  const int ll  = l & 7;                     // 16-ch group
  const int gch = ll*16;                     // first channel
  const int gh  = ll >> 1;                   // head (32 ch/head)
  float acc[16];
  #pragma unroll
  for(int i=0;i<16;i++) acc[i]=0.f;

  for(int s=sg*3; s<sg*3+3; s++){
    if(!activ[qi][s]) continue;
    const unsigned char* vb = v8 + (size_t)s*M_VAL*C_DIM + gch;
    #pragma unroll 2
    for(int p=0;p<8;p++){                    // point p <-> z-anchor d=p (P//D==1)
      const float2 r2 = refs[qi][s*8+p];
      const float ox = offs[qi][gh*16+p*2+0];
      const float oy = offs[qi][gh*16+p*2+1];
      const float x = fmaf(r2.x, (float)WF, ox - 0.5f);
      const float y = fmaf(r2.y, (float)HF, oy - 0.5f);
      const float x0f = floorf(x), y0f = floorf(y);
      const float fx = x - x0f,    fy = y - y0f;
      const int x0 = (int)x0f, y0 = (int)y0f;
      const int x1 = x0+1,     y1 = y0+1;
      const float at = attns[qi][gh*8+p];
      const float wx0 = (x0>=0 && x0<WF) ? (1.f-fx) : 0.f;
      const float wx1 = (x1>=0 && x1<WF) ? fx       : 0.f;
      const float wy0 = ((y0>=0 && y0<HF) ? (1.f-fy) : 0.f) * at;
      const float wy1 = ((y1>=0 && y1<HF) ? fy       : 0.f) * at;
      const int x0c = min(max(x0,0), WF-1), x1c = min(max(x1,0), WF-1);
      const int y0c = min(max(y0,0), HF-1), y1c = min(max(y1,0), HF-1);
      const float w00 = wx0*wy0, w01 = wx1*wy0, w10 = wx0*wy1, w11 = wx1*wy1;
      const uint4 c00 = *(const uint4*)(vb + (size_t)(y0c*WF+x0c)*C_DIM);
      const uint4 c01 = *(const uint4*)(vb + (size_t)(y0c*WF+x1c)*C_DIM);
      const uint4 c10 = *(const uint4*)(vb + (size_t)(y1c*WF+x0c)*C_DIM);
      const uint4 c11 = *(const uint4*)(vb + (size_t)(y1c*WF+x1c)*C_DIM);
      corner_acc(c00, w00, acc);
      corner_acc(c01, w01, acc);
      corner_acc(c10, w10, acc);
      corner_acc(c11, w11, acc);
    }
  }

  // ---- 4) merge cam-half partials in qs, then out-proj + residual ----
  __syncthreads();                           // all phase-2 qs reads complete
  if(sg==0){
    #pragma unroll
    for(int i=0;i<4;i++)
      *(float4*)&qs[qi][gch+i*4] = *(const float4*)&acc[i*4];
  }
  __syncthreads();
  if(sg==1){
    const float inv = cinv[qi];
    #pragma unroll
    for(int i=0;i<4;i++){
      float4 pA = *(const float4*)&qs[qi][gch+i*4];
      *(float4*)&qs[qi][gch+i*4] = make_float4((pA.x+acc[i*4+0])*inv,
                                               (pA.y+acc[i*4+1])*inv,
                                               (pA.z+acc[i*4+2])*inv,
                                               (pA.w+acc[i*4+3])*inv);
    }
  }
  __syncthreads();
  {
    const int c0 = l*8;                      // 8 output cols per lane
    const int n  = n0 + qi;
    const float4 bA = *(const float4*)&bout[c0];
    const float4 bB = *(const float4*)&bout[c0+4];
    const float4 rA = *(const float4*)&query[(size_t)n*C_DIM + c0];
    const float4 rB = *(const float4*)&query[(size_t)n*C_DIM + c0 + 4];
    float o0=bA.x+rA.x, o1=bA.y+rA.y, o2=bA.z+rA.z, o3=bA.w+rA.w;
    float o4=bB.x+rB.x, o5=bB.y+rB.y, o6=bB.z+rB.z, o7=bB.w+rB.w;
    for(int k=0;k<C_DIM;k++){
      const float sv = qs[qi][k];
      const float4 wA = *(const float4*)&Wout[(size_t)k*C_DIM + c0];
      const float4 wB = *(const float4*)&Wout[(size_t)k*C_DIM + c0 + 4];
      o0 += sv*wA.x; o1 += sv*wA.y; o2 += sv*wA.z; o3 += sv*wA.w;
      o4 += sv*wB.x; o5 += sv*wB.y; o6 += sv*wB.z; o7 += sv*wB.w;
    }
    *(float4*)&out[(size_t)n*C_DIM + c0]     = make_float4(o0,o1,o2,o3);
    *(float4*)&out[(size_t)n*C_DIM + c0 + 4] = make_float4(o4,o5,o6,o7);
  }
}

extern "C" void kernel_launch(void* const* d_in, const int* in_sizes, int n_in,
                              void* d_out, int out_size, void* d_ws, size_t ws_size,
                              hipStream_t stream){
  const float* query     = (const float*)d_in[0];
  const float* query_pos = (const float*)d_in[1];
  const float* value     = (const float*)d_in[2];
  const float* ref       = (const float*)d_in[3];
  const unsigned char* mask = (const unsigned char*)d_in[4];
  const float* Wv   = (const float*)d_in[5];
  const float* bv   = (const float*)d_in[6];
  const float* Wo   = (const float*)d_in[7];
  const float* bo   = (const float*)d_in[8];
  const float* Wa   = (const float*)d_in[9];
  const float* ba   = (const float*)d_in[10];
  const float* Wout = (const float*)d_in[11];
  const float* bout = (const float*)d_in[12];
  float* out = (float*)d_out;

  int* flag = (int*)d_ws;
  unsigned char* v8 = (unsigned char*)((char*)d_ws + 64);

  value_proj_kernel<<<(S_CAM*M_VAL)/8, 256, 0, stream>>>(value, Wv, bv, v8, mask, flag);
  fused_deform_kernel<<<N_Q/QPB, 256, 0, stream>>>(v8, query, query_pos,
                                                   Wo, bo, Wa, ba, ref, mask, flag,
                                                   Wout, bout, out);
}